// Round 17
// baseline (165.371 us; speedup 1.0000x reference)
//
#include <hip/hip_runtime.h>
#include <hip/hip_bf16.h>

typedef __bf16 bf16;
typedef __bf16 bf16x4 __attribute__((ext_vector_type(4)));
typedef __bf16 bf16x8 __attribute__((ext_vector_type(8)));
typedef float  f32x4 __attribute__((ext_vector_type(4)));

#define MFMA16(a, b, c) __builtin_amdgcn_mfma_f32_16x16x32_bf16((a), (b), (c), 0, 0, 0)

// async 16B/lane global->LDS (m97). LDS dst = uniform base + lane*16.
#define GLOBAL_LOAD_LDS16(gp, lp)                                                     \
    __builtin_amdgcn_global_load_lds(                                                 \
        (const __attribute__((address_space(1))) void*)(gp),                          \
        (__attribute__((address_space(3))) void*)(lp), 16, 0, 0)

// ---------------------------------------------------------------------------
// fp32 -> bf16, three sources in ONE launch (R11, kept: measured gain).
__global__ __launch_bounds__(256)
void cvt3(const float* __restrict__ s1, const float* __restrict__ s2,
          const float* __restrict__ s3, bf16* __restrict__ d12,
          bf16* __restrict__ d3, int n1, int n12, int ntot)
{
    int i = blockIdx.x * 256 + threadIdx.x;
    if (i >= ntot) return;
    const float* s;
    bf16* d;
    if (i < n12) {
        s = (i < n1) ? s1 + (size_t)i * 8 : s2 + (size_t)(i - n1) * 8;
        d = d12 + (size_t)i * 8;
    } else {
        s = s3 + (size_t)(i - n12) * 8;
        d = d3 + (size_t)(i - n12) * 8;
    }
    f32x4 a = *reinterpret_cast<const f32x4*>(s);
    f32x4 b = *reinterpret_cast<const f32x4*>(s + 4);
    bf16x8 r;
#pragma unroll
    for (int u = 0; u < 4; u++) { r[u] = (bf16)a[u]; r[u + 4] = (bf16)b[u]; }
    *reinterpret_cast<bf16x8*>(d) = r;
}

// ---------------------------------------------------------------------------
// QKV projection (R2 T4 pipeline + R10 swizzle; R17 adds T1 XCD-chunking).
template<bool QKPATH>
__device__ __forceinline__
void qkv_body(const bf16* __restrict__ A, const bf16* __restrict__ B,
              bf16* __restrict__ qk, bf16* __restrict__ vt,
              bf16* As, bf16* Bs, int m0, int n0)
{
    constexpr int M = 4096;
    const int t = threadIdx.x;
    const int w = t >> 6, lane = t & 63, quad = lane >> 4, ln16 = lane & 15;
    const int wr = (w >> 1) * 64, wc = (w & 1) * 64;
    const int srow = lane >> 2;
    const int scolsw = (((lane & 3) ^ ((lane >> 3) & 3)) * 8);
    const int qsw = quad ^ ((ln16 >> 1) & 3);

    f32x4 acc[4][4] = {};

    auto stage = [&](int s) {
        const int kc = s * 32;
        bf16* Ad = As + (s % 3) * 4096;
        bf16* Bd = Bs + (s % 3) * 4096;
#pragma unroll
        for (int p = 0; p < 2; p++) {
            const int o = w * 2 + p;
            GLOBAL_LOAD_LDS16(A + (size_t)(m0 + o * 16 + srow) * 1024 + kc + scolsw,
                              Ad + o * 512);
            GLOBAL_LOAD_LDS16(B + (size_t)(n0 + o * 16 + srow) * 1024 + kc + scolsw,
                              Bd + o * 512);
        }
    };

    stage(0);
    stage(1);

    for (int s = 0; s < 32; s++) {
        if (s < 30) {
            stage(s + 2);
            asm volatile("s_waitcnt vmcnt(8)" ::: "memory");
        } else if (s == 30) {
            asm volatile("s_waitcnt vmcnt(4)" ::: "memory");
        } else {
            asm volatile("s_waitcnt vmcnt(0)" ::: "memory");
        }
        __builtin_amdgcn_s_barrier();
        __builtin_amdgcn_sched_barrier(0);

        const bf16* Ab = As + (s % 3) * 4096;
        const bf16* Bb = Bs + (s % 3) * 4096;
        bf16x8 af[4];
#pragma unroll
        for (int mb = 0; mb < 4; mb++)
            af[mb] = *reinterpret_cast<const bf16x8*>(
                Ab + (wr + mb * 16 + ln16) * 32 + qsw * 8);
#pragma unroll
        for (int nb = 0; nb < 4; nb++) {
            bf16x8 bv = *reinterpret_cast<const bf16x8*>(
                Bb + (wc + nb * 16 + ln16) * 32 + qsw * 8);
#pragma unroll
            for (int mb = 0; mb < 4; mb++) {
                if constexpr (QKPATH) acc[mb][nb] = MFMA16(bv, af[mb], acc[mb][nb]);
                else                  acc[mb][nb] = MFMA16(af[mb], bv, acc[mb][nb]);
            }
        }

        __builtin_amdgcn_sched_barrier(0);
        __builtin_amdgcn_s_barrier();
    }

    if constexpr (QKPATH) {
#pragma unroll
        for (int mb = 0; mb < 4; mb++)
#pragma unroll
            for (int nb = 0; nb < 4; nb++) {
                size_t idx = (size_t)(m0 + wr + mb * 16 + ln16) * 2048
                           + (n0 + wc + nb * 16 + quad * 4);
                bf16x4 v;
#pragma unroll
                for (int r = 0; r < 4; r++) v[r] = (bf16)acc[mb][nb][r];
                *reinterpret_cast<bf16x4*>(&qk[idx]) = v;
            }
    } else {
#pragma unroll
        for (int mb = 0; mb < 4; mb++)
#pragma unroll
            for (int nb = 0; nb < 4; nb++) {
                const int e = n0 - 2048 + wc + nb * 16 + ln16;
                size_t idx = (size_t)e * M + (m0 + wr + mb * 16 + quad * 4);
                bf16x4 v;
#pragma unroll
                for (int r = 0; r < 4; r++) v[r] = (bf16)acc[mb][nb][r];
                *reinterpret_cast<bf16x4*>(&vt[idx]) = v;
            }
    }
}

__global__ __launch_bounds__(256)
void gemm_qkv(const bf16* __restrict__ A, const bf16* __restrict__ B,
              bf16* __restrict__ qk, bf16* __restrict__ vt)
{
    __shared__ __align__(16) bf16 As[12288];  // 3 rotating [128][32] buffers
    __shared__ __align__(16) bf16 Bs[12288];
    // T1 XCD-chunk swizzle (R17): 768 blocks = 8 XCDs x (8 m-tiles x 12
    // n-tiles); per-XCD working set A 2MB + B 3MB ~ L2. Bijective: 768%8==0.
    const int bid = blockIdx.x;
    const int xcd = bid & 7, idx = bid >> 3;       // idx 0..95
    const int xm = xcd >> 1, xn = xcd & 1;         // 4x2 XCD grid
    const int im = idx / 12, in = idx % 12;        // 8x12 tiles per XCD
    const int m0 = (xm * 8 + im) * 128;
    const int n0 = (xn * 12 + in) * 128;
    if (n0 < 2048) qkv_body<true >(A, B, qk, vt, As, Bs, m0, n0);
    else           qkv_body<false>(A, B, qk, vt, As, Bs, m0, n0);
}

// ---------------------------------------------------------------------------
// Out projection v7 (R4 structure + R10 swizzle + existing XCD chunking).
__global__ __launch_bounds__(256)
void gemm_out(const bf16* __restrict__ A, const bf16* __restrict__ Bw,
              float* __restrict__ C)
{
    __shared__ __align__(16) bf16 As[24576];  // 3 x [2 k-halves][128][32]
    __shared__ __align__(16) bf16 Bs[12288];  // 3 x [2 k-halves][ 64][32]

    const int t = threadIdx.x;
    const int w = t >> 6, lane = t & 63, quad = lane >> 4, ln16 = lane & 15;

    const int bid = blockIdx.x;
    const int xcd = bid & 7, idx = bid >> 3;
    const int m0 = (xcd * 4 + (idx >> 4)) * 128;
    const int n0 = (idx & 15) * 64;

    const int wr = (w >> 1) * 64, wc = (w & 1) * 32;
    const int srow = lane >> 2;
    const int scolsw = (((lane & 3) ^ ((lane >> 3) & 3)) * 8);
    const int qsw = quad ^ ((ln16 >> 1) & 3);

    f32x4 acc[4][2] = {};

    auto stage = [&](int s) {
        const int k0 = s * 64;
        bf16* Ad = As + (s % 3) * 8192;
        bf16* Bd = Bs + (s % 3) * 4096;
#pragma unroll
        for (int p = 0; p < 4; p++) {
            const int i = w * 4 + p;
            const int h = i >> 3, o = i & 7;
            GLOBAL_LOAD_LDS16(A + (size_t)(m0 + o * 16 + srow) * 1024 + k0 + h * 32 + scolsw,
                              Ad + h * 4096 + o * 512);
        }
#pragma unroll
        for (int p = 0; p < 2; p++) {
            const int i = w * 2 + p;
            const int h = i >> 2, o = i & 3;
            GLOBAL_LOAD_LDS16(Bw + (size_t)(n0 + o * 16 + srow) * 1024 + k0 + h * 32 + scolsw,
                              Bd + h * 2048 + o * 512);
        }
    };

    stage(0);
    stage(1);

    for (int s = 0; s < 16; s++) {
        if (s < 14) {
            stage(s + 2);
            asm volatile("s_waitcnt vmcnt(12)" ::: "memory");
        } else if (s == 14) {
            asm volatile("s_waitcnt vmcnt(6)" ::: "memory");
        } else {
            asm volatile("s_waitcnt vmcnt(0)" ::: "memory");
        }
        __builtin_amdgcn_s_barrier();
        __builtin_amdgcn_sched_barrier(0);

        const bf16* Ab = As + (s % 3) * 8192;
        const bf16* Bb = Bs + (s % 3) * 4096;
#pragma unroll
        for (int kki = 0; kki < 2; kki++) {
            bf16x8 af[4];
#pragma unroll
            for (int mb = 0; mb < 4; mb++)
                af[mb] = *reinterpret_cast<const bf16x8*>(
                    Ab + kki * 4096 + (wr + mb * 16 + ln16) * 32 + qsw * 8);
#pragma unroll
            for (int nb = 0; nb < 2; nb++) {
                bf16x8 bv = *reinterpret_cast<const bf16x8*>(
                    Bb + kki * 2048 + (wc + nb * 16 + ln16) * 32 + qsw * 8);
#pragma unroll
                for (int mb = 0; mb < 4; mb++)
                    acc[mb][nb] = MFMA16(bv, af[mb], acc[mb][nb]);  // swapped
            }
        }

        __builtin_amdgcn_sched_barrier(0);
        __builtin_amdgcn_s_barrier();
    }

#pragma unroll
    for (int mb = 0; mb < 4; mb++)
#pragma unroll
        for (int nb = 0; nb < 2; nb++) {
            size_t idx = (size_t)(m0 + wr + mb * 16 + ln16) * 1024
                       + (n0 + wc + nb * 16 + quad * 4);
            *reinterpret_cast<f32x4*>(&C[idx]) = acc[mb][nb];
        }
}

// ---------------------------------------------------------------------------
// Fused causal flash attention v9 (R14 paired q-tiles, measured ~40us) +
// R17 T1 XCD-chunking: per XCD 4 (b,h)-groups x all 16 qp -> 16 blocks share
// each group's 512KB K/V in L2 (2MB/XCD working set). Bijective: 512%8==0.
__global__ __launch_bounds__(256)
void attn_flash9(const bf16* __restrict__ qk, const bf16* __restrict__ vt,
                 bf16* __restrict__ z)
{
    constexpr int Tn = 2048, Dm = 1024, QLD = 2048, VLD = 4096;
    __shared__ __align__(16) bf16 Ks[8192];   // 2 x [64][64], swizzled
    __shared__ __align__(16) bf16 VTs[8192];  // 2 x [64][64], swizzled
    __shared__ __align__(16) bf16 Ps1[4096];  // [64][64], tile-1 P
    __shared__ __align__(16) bf16 Ps2[4096];  // [64][64], tile-2 P

    const int t = threadIdx.x;
    const int w = t >> 6, lane = t & 63, quad = lane >> 4, ln16 = lane & 15;
    // T1 swizzle: xcd = bid&7 gets groups [4*xcd, 4*xcd+4) x qp 0..15
    const int bid = blockIdx.x;
    const int xcd = bid & 7, idx = bid >> 3;       // idx 0..63
    const int g = xcd * 4 + (idx >> 4);            // 0..31
    const int qp = idx & 15;                       // 0..15
    const int j1 = qp, j2 = 31 - qp;               // j1 <= 15 < j2
    const int b = g >> 4, h = g & 15;
    const int q01 = j1 * 64, q02 = j2 * 64;

    const bf16* Qb = qk + (size_t)b * Tn * QLD + h * 64;
    const bf16* Kb = Qb + 1024;
    const bf16* Vb = vt + (size_t)(h * 64) * VLD + b * Tn;

    constexpr float C2 = 0.125f * 1.44269504089f;
    bf16x8 qf1[2], qf2[2];
#pragma unroll
    for (int kki = 0; kki < 2; kki++) {
        bf16x8 qv1 = *reinterpret_cast<const bf16x8*>(
            Qb + (size_t)(q01 + w * 16 + ln16) * QLD + kki * 32 + quad * 8);
        bf16x8 qv2 = *reinterpret_cast<const bf16x8*>(
            Qb + (size_t)(q02 + w * 16 + ln16) * QLD + kki * 32 + quad * 8);
#pragma unroll
        for (int u = 0; u < 8; u++) {
            qf1[kki][u] = (bf16)((float)qv1[u] * C2);
            qf2[kki][u] = (bf16)((float)qv2[u] * C2);
        }
    }

    bf16x8 vones;
#pragma unroll
    for (int u = 0; u < 8; u++) vones[u] = (bf16)1.0f;

    const int sr = t >> 3;            // staging row 0..31 (+p*32)
    const int sseg = (t & 7) * 8;     // staging col (elems)
    const int rsw = (ln16 & 7) << 3;  // read-side swizzle (row&7 == ln16&7)

    bf16x8 kreg[2], vreg[2];
#pragma unroll
    for (int p = 0; p < 2; p++) {
        kreg[p] = *reinterpret_cast<const bf16x8*>(Kb + (size_t)(sr + p * 32) * QLD + sseg);
        vreg[p] = *reinterpret_cast<const bf16x8*>(Vb + (size_t)(sr + p * 32) * VLD + sseg);
    }

    f32x4 accO1[5] = {}, accO2[5] = {};
    const int qloc = w * 16 + ln16;

    for (int kt = 0; kt <= j2; kt++) {
        const int cur = (kt & 1) * 4096;
#pragma unroll
        for (int p = 0; p < 2; p++) {
            const int r = sr + p * 32;
            const int co = sseg ^ ((r & 7) << 3);
            *reinterpret_cast<bf16x8*>(&Ks[cur + r * 64 + co]) = kreg[p];
            *reinterpret_cast<bf16x8*>(&VTs[cur + r * 64 + co]) = vreg[p];
        }
        __syncthreads();   // single barrier per kt (v8 structure)

        if (kt < j2) {     // global prefetch kt+1, hides under QK/PV below
            const int k1 = (kt + 1) * 64;
#pragma unroll
            for (int p = 0; p < 2; p++) {
                kreg[p] = *reinterpret_cast<const bf16x8*>(
                    Kb + (size_t)(k1 + sr + p * 32) * QLD + sseg);
                vreg[p] = *reinterpret_cast<const bf16x8*>(
                    Vb + (size_t)(sr + p * 32) * VLD + k1 + sseg);
            }
        }
        const bool t1 = (kt <= j1);   // block-uniform

        // ---- QK^T tile 2 (always) ----
        f32x4 aS2[4] = {};
#pragma unroll
        for (int kki = 0; kki < 2; kki++)
#pragma unroll
            for (int nb = 0; nb < 4; nb++) {
                bf16x8 kb = *reinterpret_cast<const bf16x8*>(
                    &Ks[cur + (nb * 16 + ln16) * 64 + ((kki * 32 + quad * 8) ^ rsw)]);
                aS2[nb] = MFMA16(kb, qf2[kki], aS2[nb]);
            }
        if (kt == j2) {
#pragma unroll
            for (int nb = 0; nb < 4; nb++) {
                bf16x4 pv;
#pragma unroll
                for (int r = 0; r < 4; r++) {
                    float p = __builtin_amdgcn_exp2f(aS2[nb][r]);
                    if ((nb * 16 + quad * 4 + r) > qloc) p = 0.f;
                    pv[r] = (bf16)p;
                }
                *reinterpret_cast<bf16x4*>(
                    &Ps2[qloc * 64 + ((nb * 16 + quad * 4) ^ rsw)]) = pv;
            }
        } else {
#pragma unroll
            for (int nb = 0; nb < 4; nb++) {
                bf16x4 pv;
#pragma unroll
                for (int r = 0; r < 4; r++)
                    pv[r] = (bf16)__builtin_amdgcn_exp2f(aS2[nb][r]);
                *reinterpret_cast<bf16x4*>(
                    &Ps2[qloc * 64 + ((nb * 16 + quad * 4) ^ rsw)]) = pv;
            }
        }

        // ---- QK^T tile 1 (while active) ----
        if (t1) {
            f32x4 aS1[4] = {};
#pragma unroll
            for (int kki = 0; kki < 2; kki++)
#pragma unroll
                for (int nb = 0; nb < 4; nb++) {
                    bf16x8 kb = *reinterpret_cast<const bf16x8*>(
                        &Ks[cur + (nb * 16 + ln16) * 64 + ((kki * 32 + quad * 8) ^ rsw)]);
                    aS1[nb] = MFMA16(kb, qf1[kki], aS1[nb]);
                }
            if (kt == j1) {
#pragma unroll
                for (int nb = 0; nb < 4; nb++) {
                    bf16x4 pv;
#pragma unroll
                    for (int r = 0; r < 4; r++) {
                        float p = __builtin_amdgcn_exp2f(aS1[nb][r]);
                        if ((nb * 16 + quad * 4 + r) > qloc) p = 0.f;
                        pv[r] = (bf16)p;
                    }
                    *reinterpret_cast<bf16x4*>(
                        &Ps1[qloc * 64 + ((nb * 16 + quad * 4) ^ rsw)]) = pv;
                }
            } else {
#pragma unroll
                for (int nb = 0; nb < 4; nb++) {
                    bf16x4 pv;
#pragma unroll
                    for (int r = 0; r < 4; r++)
                        pv[r] = (bf16)__builtin_amdgcn_exp2f(aS1[nb][r]);
                    *reinterpret_cast<bf16x4*>(
                        &Ps1[qloc * 64 + ((nb * 16 + quad * 4) ^ rsw)]) = pv;
                }
            }
        }
        asm volatile("s_waitcnt lgkmcnt(0)" ::: "memory");

        // ---- PV (tile 2 always, tile 1 while active) ----
#pragma unroll
        for (int kki = 0; kki < 2; kki++) {
            bf16x8 pa2 = *reinterpret_cast<const bf16x8*>(
                &Ps2[qloc * 64 + ((kki * 32 + quad * 8) ^ rsw)]);
#pragma unroll
            for (int nb = 0; nb < 4; nb++) {
                bf16x8 vb = *reinterpret_cast<const bf16x8*>(
                    &VTs[cur + (nb * 16 + ln16) * 64 + ((kki * 32 + quad * 8) ^ rsw)]);
                accO2[nb] = MFMA16(vb, pa2, accO2[nb]);
            }
            accO2[4] = MFMA16(vones, pa2, accO2[4]);
        }
        if (t1) {
#pragma unroll
            for (int kki = 0; kki < 2; kki++) {
                bf16x8 pa1 = *reinterpret_cast<const bf16x8*>(
                    &Ps1[qloc * 64 + ((kki * 32 + quad * 8) ^ rsw)]);
#pragma unroll
                for (int nb = 0; nb < 4; nb++) {
                    bf16x8 vb = *reinterpret_cast<const bf16x8*>(
                        &VTs[cur + (nb * 16 + ln16) * 64 + ((kki * 32 + quad * 8) ^ rsw)]);
                    accO1[nb] = MFMA16(vb, pa1, accO1[nb]);
                }
                accO1[4] = MFMA16(vones, pa1, accO1[4]);
            }
        }
    }

    const float linv1 = 1.0f / accO1[4][0];
    const float linv2 = 1.0f / accO2[4][0];
    const size_t zr1 = ((size_t)b * Tn + q01 + qloc) * Dm + h * 64;
    const size_t zr2 = ((size_t)b * Tn + q02 + qloc) * Dm + h * 64;
#pragma unroll
    for (int nb = 0; nb < 4; nb++) {
        bf16x4 v1, v2;
#pragma unroll
        for (int r = 0; r < 4; r++) {
            v1[r] = (bf16)(accO1[nb][r] * linv1);
            v2[r] = (bf16)(accO2[nb][r] * linv2);
        }
        *reinterpret_cast<bf16x4*>(z + zr1 + nb * 16 + quad * 4) = v1;
        *reinterpret_cast<bf16x4*>(z + zr2 + nb * 16 + quad * 4) = v2;
    }
}

// ---------------------------------------------------------------------------
extern "C" void kernel_launch(void* const* d_in, const int* in_sizes, int n_in,
                              void* d_out, int out_size, void* d_ws, size_t ws_size,
                              hipStream_t stream)
{
    constexpr int B = 2, T = 2048, D = 1024;
    constexpr int M = B * T;  // 4096

    const float* X    = (const float*)d_in[0];
    const float* Wqkv = (const float*)d_in[1];
    const float* Wout = (const float*)d_in[2];
    float* out = (float*)d_out;

    // ws: qk [M][2048] 16 MiB | vt [1024][M] 8 MiB | z [M][1024] 8 MiB
    //   | Woutbf [1024][1024] 2 MiB
    bf16* qk  = (bf16*)d_ws;
    bf16* vt  = qk + (size_t)M * 2048;
    bf16* zbf = vt + (size_t)1024 * M;
    bf16* Woutbf = zbf + (size_t)M * 1024;
    // d_out as scratch until gemm_out writes it (Xbf 8 MiB + Wqkvbf 6 MiB <= 16)
    bf16* Xbf    = (bf16*)d_out;
    bf16* Wqkvbf = Xbf + (size_t)M * D;

    dim3 blk(256);
    const int n1 = M * D / 8, n2 = 3 * D * D / 8, n3 = D * D / 8;
    cvt3<<<(n1 + n2 + n3 + 255) / 256, blk, 0, stream>>>(
        X, Wqkv, Wout, Xbf, Woutbf, n1, n1 + n2, n1 + n2 + n3);

    gemm_qkv<<<dim3(768), blk, 0, stream>>>(Xbf, Wqkvbf, qk, vt);

    attn_flash9<<<dim3(512), blk, 0, stream>>>(qk, vt, zbf);

    gemm_out<<<dim3(512), blk, 0, stream>>>(zbf, Woutbf, out);
}

// Round 18
// 163.666 us; speedup vs baseline: 1.0104x; 1.0104x over previous
//
#include <hip/hip_runtime.h>
#include <hip/hip_bf16.h>

typedef __bf16 bf16;
typedef __bf16 bf16x4 __attribute__((ext_vector_type(4)));
typedef __bf16 bf16x8 __attribute__((ext_vector_type(8)));
typedef float  f32x4 __attribute__((ext_vector_type(4)));

#define MFMA16(a, b, c) __builtin_amdgcn_mfma_f32_16x16x32_bf16((a), (b), (c), 0, 0, 0)

// async 16B/lane global->LDS (m97). LDS dst = uniform base + lane*16.
#define GLOBAL_LOAD_LDS16(gp, lp)                                                     \
    __builtin_amdgcn_global_load_lds(                                                 \
        (const __attribute__((address_space(1))) void*)(gp),                          \
        (__attribute__((address_space(3))) void*)(lp), 16, 0, 0)

// ---------------------------------------------------------------------------
// fp32 -> bf16, three sources in ONE launch (R11, kept: measured gain).
__global__ __launch_bounds__(256)
void cvt3(const float* __restrict__ s1, const float* __restrict__ s2,
          const float* __restrict__ s3, bf16* __restrict__ d12,
          bf16* __restrict__ d3, int n1, int n12, int ntot)
{
    int i = blockIdx.x * 256 + threadIdx.x;
    if (i >= ntot) return;
    const float* s;
    bf16* d;
    if (i < n12) {
        s = (i < n1) ? s1 + (size_t)i * 8 : s2 + (size_t)(i - n1) * 8;
        d = d12 + (size_t)i * 8;
    } else {
        s = s3 + (size_t)(i - n12) * 8;
        d = d3 + (size_t)(i - n12) * 8;
    }
    f32x4 a = *reinterpret_cast<const f32x4*>(s);
    f32x4 b = *reinterpret_cast<const f32x4*>(s + 4);
    bf16x8 r;
#pragma unroll
    for (int u = 0; u < 4; u++) { r[u] = (bf16)a[u]; r[u + 4] = (bf16)b[u]; }
    *reinterpret_cast<bf16x8*>(d) = r;
}

// ---------------------------------------------------------------------------
// QKV projection (R2 T4 pipeline + R10 swizzle; R17's T1 chunking REVERTED --
// measured neutral-to-negative: kernel is structure-bound at ~90% of the
// 2-phase ceiling, not traffic-bound, so L2 locality doesn't pay).
template<bool QKPATH>
__device__ __forceinline__
void qkv_body(const bf16* __restrict__ A, const bf16* __restrict__ B,
              bf16* __restrict__ qk, bf16* __restrict__ vt,
              bf16* As, bf16* Bs, int m0, int n0)
{
    constexpr int M = 4096;
    const int t = threadIdx.x;
    const int w = t >> 6, lane = t & 63, quad = lane >> 4, ln16 = lane & 15;
    const int wr = (w >> 1) * 64, wc = (w & 1) * 64;
    const int srow = lane >> 2;
    const int scolsw = (((lane & 3) ^ ((lane >> 3) & 3)) * 8);
    const int qsw = quad ^ ((ln16 >> 1) & 3);

    f32x4 acc[4][4] = {};

    auto stage = [&](int s) {
        const int kc = s * 32;
        bf16* Ad = As + (s % 3) * 4096;
        bf16* Bd = Bs + (s % 3) * 4096;
#pragma unroll
        for (int p = 0; p < 2; p++) {
            const int o = w * 2 + p;
            GLOBAL_LOAD_LDS16(A + (size_t)(m0 + o * 16 + srow) * 1024 + kc + scolsw,
                              Ad + o * 512);
            GLOBAL_LOAD_LDS16(B + (size_t)(n0 + o * 16 + srow) * 1024 + kc + scolsw,
                              Bd + o * 512);
        }
    };

    stage(0);
    stage(1);

    for (int s = 0; s < 32; s++) {
        if (s < 30) {
            stage(s + 2);
            asm volatile("s_waitcnt vmcnt(8)" ::: "memory");
        } else if (s == 30) {
            asm volatile("s_waitcnt vmcnt(4)" ::: "memory");
        } else {
            asm volatile("s_waitcnt vmcnt(0)" ::: "memory");
        }
        __builtin_amdgcn_s_barrier();
        __builtin_amdgcn_sched_barrier(0);

        const bf16* Ab = As + (s % 3) * 4096;
        const bf16* Bb = Bs + (s % 3) * 4096;
        bf16x8 af[4];
#pragma unroll
        for (int mb = 0; mb < 4; mb++)
            af[mb] = *reinterpret_cast<const bf16x8*>(
                Ab + (wr + mb * 16 + ln16) * 32 + qsw * 8);
#pragma unroll
        for (int nb = 0; nb < 4; nb++) {
            bf16x8 bv = *reinterpret_cast<const bf16x8*>(
                Bb + (wc + nb * 16 + ln16) * 32 + qsw * 8);
#pragma unroll
            for (int mb = 0; mb < 4; mb++) {
                if constexpr (QKPATH) acc[mb][nb] = MFMA16(bv, af[mb], acc[mb][nb]);
                else                  acc[mb][nb] = MFMA16(af[mb], bv, acc[mb][nb]);
            }
        }

        __builtin_amdgcn_sched_barrier(0);
        __builtin_amdgcn_s_barrier();
    }

    if constexpr (QKPATH) {
#pragma unroll
        for (int mb = 0; mb < 4; mb++)
#pragma unroll
            for (int nb = 0; nb < 4; nb++) {
                size_t idx = (size_t)(m0 + wr + mb * 16 + ln16) * 2048
                           + (n0 + wc + nb * 16 + quad * 4);
                bf16x4 v;
#pragma unroll
                for (int r = 0; r < 4; r++) v[r] = (bf16)acc[mb][nb][r];
                *reinterpret_cast<bf16x4*>(&qk[idx]) = v;
            }
    } else {
#pragma unroll
        for (int mb = 0; mb < 4; mb++)
#pragma unroll
            for (int nb = 0; nb < 4; nb++) {
                const int e = n0 - 2048 + wc + nb * 16 + ln16;
                size_t idx = (size_t)e * M + (m0 + wr + mb * 16 + quad * 4);
                bf16x4 v;
#pragma unroll
                for (int r = 0; r < 4; r++) v[r] = (bf16)acc[mb][nb][r];
                *reinterpret_cast<bf16x4*>(&vt[idx]) = v;
            }
    }
}

__global__ __launch_bounds__(256)
void gemm_qkv(const bf16* __restrict__ A, const bf16* __restrict__ B,
              bf16* __restrict__ qk, bf16* __restrict__ vt)
{
    __shared__ __align__(16) bf16 As[12288];  // 3 rotating [128][32] buffers
    __shared__ __align__(16) bf16 Bs[12288];
    const int m0 = blockIdx.y * 128, n0 = blockIdx.x * 128;
    if (n0 < 2048) qkv_body<true >(A, B, qk, vt, As, Bs, m0, n0);
    else           qkv_body<false>(A, B, qk, vt, As, Bs, m0, n0);
}

// ---------------------------------------------------------------------------
// Out projection v7 (R4 structure + R10 swizzle + original XCD chunking).
__global__ __launch_bounds__(256)
void gemm_out(const bf16* __restrict__ A, const bf16* __restrict__ Bw,
              float* __restrict__ C)
{
    __shared__ __align__(16) bf16 As[24576];  // 3 x [2 k-halves][128][32]
    __shared__ __align__(16) bf16 Bs[12288];  // 3 x [2 k-halves][ 64][32]

    const int t = threadIdx.x;
    const int w = t >> 6, lane = t & 63, quad = lane >> 4, ln16 = lane & 15;

    const int bid = blockIdx.x;
    const int xcd = bid & 7, idx = bid >> 3;
    const int m0 = (xcd * 4 + (idx >> 4)) * 128;
    const int n0 = (idx & 15) * 64;

    const int wr = (w >> 1) * 64, wc = (w & 1) * 32;
    const int srow = lane >> 2;
    const int scolsw = (((lane & 3) ^ ((lane >> 3) & 3)) * 8);
    const int qsw = quad ^ ((ln16 >> 1) & 3);

    f32x4 acc[4][2] = {};

    auto stage = [&](int s) {
        const int k0 = s * 64;
        bf16* Ad = As + (s % 3) * 8192;
        bf16* Bd = Bs + (s % 3) * 4096;
#pragma unroll
        for (int p = 0; p < 4; p++) {
            const int i = w * 4 + p;
            const int h = i >> 3, o = i & 7;
            GLOBAL_LOAD_LDS16(A + (size_t)(m0 + o * 16 + srow) * 1024 + k0 + h * 32 + scolsw,
                              Ad + h * 4096 + o * 512);
        }
#pragma unroll
        for (int p = 0; p < 2; p++) {
            const int i = w * 2 + p;
            const int h = i >> 2, o = i & 3;
            GLOBAL_LOAD_LDS16(Bw + (size_t)(n0 + o * 16 + srow) * 1024 + k0 + h * 32 + scolsw,
                              Bd + h * 2048 + o * 512);
        }
    };

    stage(0);
    stage(1);

    for (int s = 0; s < 16; s++) {
        if (s < 14) {
            stage(s + 2);
            asm volatile("s_waitcnt vmcnt(12)" ::: "memory");
        } else if (s == 14) {
            asm volatile("s_waitcnt vmcnt(6)" ::: "memory");
        } else {
            asm volatile("s_waitcnt vmcnt(0)" ::: "memory");
        }
        __builtin_amdgcn_s_barrier();
        __builtin_amdgcn_sched_barrier(0);

        const bf16* Ab = As + (s % 3) * 8192;
        const bf16* Bb = Bs + (s % 3) * 4096;
#pragma unroll
        for (int kki = 0; kki < 2; kki++) {
            bf16x8 af[4];
#pragma unroll
            for (int mb = 0; mb < 4; mb++)
                af[mb] = *reinterpret_cast<const bf16x8*>(
                    Ab + kki * 4096 + (wr + mb * 16 + ln16) * 32 + qsw * 8);
#pragma unroll
            for (int nb = 0; nb < 2; nb++) {
                bf16x8 bv = *reinterpret_cast<const bf16x8*>(
                    Bb + kki * 2048 + (wc + nb * 16 + ln16) * 32 + qsw * 8);
#pragma unroll
                for (int mb = 0; mb < 4; mb++)
                    acc[mb][nb] = MFMA16(bv, af[mb], acc[mb][nb]);  // swapped
            }
        }

        __builtin_amdgcn_sched_barrier(0);
        __builtin_amdgcn_s_barrier();
    }

#pragma unroll
    for (int mb = 0; mb < 4; mb++)
#pragma unroll
        for (int nb = 0; nb < 2; nb++) {
            size_t idx = (size_t)(m0 + wr + mb * 16 + ln16) * 1024
                       + (n0 + wc + nb * 16 + quad * 4);
            *reinterpret_cast<f32x4*>(&C[idx]) = acc[mb][nb];
        }
}

// ---------------------------------------------------------------------------
// Fused causal flash attention v9 (R14 paired q-tiles; R17's T1 chunking
// REVERTED -- measured neutral, kernel is latency-bound not traffic-bound).
__global__ __launch_bounds__(256)
void attn_flash9(const bf16* __restrict__ qk, const bf16* __restrict__ vt,
                 bf16* __restrict__ z)
{
    constexpr int Tn = 2048, Dm = 1024, QLD = 2048, VLD = 4096;
    __shared__ __align__(16) bf16 Ks[8192];   // 2 x [64][64], swizzled
    __shared__ __align__(16) bf16 VTs[8192];  // 2 x [64][64], swizzled
    __shared__ __align__(16) bf16 Ps1[4096];  // [64][64], tile-1 P
    __shared__ __align__(16) bf16 Ps2[4096];  // [64][64], tile-2 P

    const int t = threadIdx.x;
    const int w = t >> 6, lane = t & 63, quad = lane >> 4, ln16 = lane & 15;
    const int qp = blockIdx.x >> 5, g = blockIdx.x & 31;
    const int j1 = qp, j2 = 31 - qp;          // j1 <= 15 < j2
    const int b = g >> 4, h = g & 15;
    const int q01 = j1 * 64, q02 = j2 * 64;

    const bf16* Qb = qk + (size_t)b * Tn * QLD + h * 64;
    const bf16* Kb = Qb + 1024;
    const bf16* Vb = vt + (size_t)(h * 64) * VLD + b * Tn;

    constexpr float C2 = 0.125f * 1.44269504089f;
    bf16x8 qf1[2], qf2[2];
#pragma unroll
    for (int kki = 0; kki < 2; kki++) {
        bf16x8 qv1 = *reinterpret_cast<const bf16x8*>(
            Qb + (size_t)(q01 + w * 16 + ln16) * QLD + kki * 32 + quad * 8);
        bf16x8 qv2 = *reinterpret_cast<const bf16x8*>(
            Qb + (size_t)(q02 + w * 16 + ln16) * QLD + kki * 32 + quad * 8);
#pragma unroll
        for (int u = 0; u < 8; u++) {
            qf1[kki][u] = (bf16)((float)qv1[u] * C2);
            qf2[kki][u] = (bf16)((float)qv2[u] * C2);
        }
    }

    bf16x8 vones;
#pragma unroll
    for (int u = 0; u < 8; u++) vones[u] = (bf16)1.0f;

    const int sr = t >> 3;            // staging row 0..31 (+p*32)
    const int sseg = (t & 7) * 8;     // staging col (elems)
    const int rsw = (ln16 & 7) << 3;  // read-side swizzle (row&7 == ln16&7)

    bf16x8 kreg[2], vreg[2];
#pragma unroll
    for (int p = 0; p < 2; p++) {
        kreg[p] = *reinterpret_cast<const bf16x8*>(Kb + (size_t)(sr + p * 32) * QLD + sseg);
        vreg[p] = *reinterpret_cast<const bf16x8*>(Vb + (size_t)(sr + p * 32) * VLD + sseg);
    }

    f32x4 accO1[5] = {}, accO2[5] = {};
    const int qloc = w * 16 + ln16;

    for (int kt = 0; kt <= j2; kt++) {
        const int cur = (kt & 1) * 4096;
#pragma unroll
        for (int p = 0; p < 2; p++) {
            const int r = sr + p * 32;
            const int co = sseg ^ ((r & 7) << 3);
            *reinterpret_cast<bf16x8*>(&Ks[cur + r * 64 + co]) = kreg[p];
            *reinterpret_cast<bf16x8*>(&VTs[cur + r * 64 + co]) = vreg[p];
        }
        __syncthreads();   // single barrier per kt (v8 structure)

        if (kt < j2) {     // global prefetch kt+1, hides under QK/PV below
            const int k1 = (kt + 1) * 64;
#pragma unroll
            for (int p = 0; p < 2; p++) {
                kreg[p] = *reinterpret_cast<const bf16x8*>(
                    Kb + (size_t)(k1 + sr + p * 32) * QLD + sseg);
                vreg[p] = *reinterpret_cast<const bf16x8*>(
                    Vb + (size_t)(sr + p * 32) * VLD + k1 + sseg);
            }
        }
        const bool t1 = (kt <= j1);   // block-uniform

        // ---- QK^T tile 2 (always) ----
        f32x4 aS2[4] = {};
#pragma unroll
        for (int kki = 0; kki < 2; kki++)
#pragma unroll
            for (int nb = 0; nb < 4; nb++) {
                bf16x8 kb = *reinterpret_cast<const bf16x8*>(
                    &Ks[cur + (nb * 16 + ln16) * 64 + ((kki * 32 + quad * 8) ^ rsw)]);
                aS2[nb] = MFMA16(kb, qf2[kki], aS2[nb]);
            }
        if (kt == j2) {
#pragma unroll
            for (int nb = 0; nb < 4; nb++) {
                bf16x4 pv;
#pragma unroll
                for (int r = 0; r < 4; r++) {
                    float p = __builtin_amdgcn_exp2f(aS2[nb][r]);
                    if ((nb * 16 + quad * 4 + r) > qloc) p = 0.f;
                    pv[r] = (bf16)p;
                }
                *reinterpret_cast<bf16x4*>(
                    &Ps2[qloc * 64 + ((nb * 16 + quad * 4) ^ rsw)]) = pv;
            }
        } else {
#pragma unroll
            for (int nb = 0; nb < 4; nb++) {
                bf16x4 pv;
#pragma unroll
                for (int r = 0; r < 4; r++)
                    pv[r] = (bf16)__builtin_amdgcn_exp2f(aS2[nb][r]);
                *reinterpret_cast<bf16x4*>(
                    &Ps2[qloc * 64 + ((nb * 16 + quad * 4) ^ rsw)]) = pv;
            }
        }

        // ---- QK^T tile 1 (while active) ----
        if (t1) {
            f32x4 aS1[4] = {};
#pragma unroll
            for (int kki = 0; kki < 2; kki++)
#pragma unroll
                for (int nb = 0; nb < 4; nb++) {
                    bf16x8 kb = *reinterpret_cast<const bf16x8*>(
                        &Ks[cur + (nb * 16 + ln16) * 64 + ((kki * 32 + quad * 8) ^ rsw)]);
                    aS1[nb] = MFMA16(kb, qf1[kki], aS1[nb]);
                }
            if (kt == j1) {
#pragma unroll
                for (int nb = 0; nb < 4; nb++) {
                    bf16x4 pv;
#pragma unroll
                    for (int r = 0; r < 4; r++) {
                        float p = __builtin_amdgcn_exp2f(aS1[nb][r]);
                        if ((nb * 16 + quad * 4 + r) > qloc) p = 0.f;
                        pv[r] = (bf16)p;
                    }
                    *reinterpret_cast<bf16x4*>(
                        &Ps1[qloc * 64 + ((nb * 16 + quad * 4) ^ rsw)]) = pv;
                }
            } else {
#pragma unroll
                for (int nb = 0; nb < 4; nb++) {
                    bf16x4 pv;
#pragma unroll
                    for (int r = 0; r < 4; r++)
                        pv[r] = (bf16)__builtin_amdgcn_exp2f(aS1[nb][r]);
                    *reinterpret_cast<bf16x4*>(
                        &Ps1[qloc * 64 + ((nb * 16 + quad * 4) ^ rsw)]) = pv;
                }
            }
        }
        asm volatile("s_waitcnt lgkmcnt(0)" ::: "memory");

        // ---- PV (tile 2 always, tile 1 while active) ----
#pragma unroll
        for (int kki = 0; kki < 2; kki++) {
            bf16x8 pa2 = *reinterpret_cast<const bf16x8*>(
                &Ps2[qloc * 64 + ((kki * 32 + quad * 8) ^ rsw)]);
#pragma unroll
            for (int nb = 0; nb < 4; nb++) {
                bf16x8 vb = *reinterpret_cast<const bf16x8*>(
                    &VTs[cur + (nb * 16 + ln16) * 64 + ((kki * 32 + quad * 8) ^ rsw)]);
                accO2[nb] = MFMA16(vb, pa2, accO2[nb]);
            }
            accO2[4] = MFMA16(vones, pa2, accO2[4]);
        }
        if (t1) {
#pragma unroll
            for (int kki = 0; kki < 2; kki++) {
                bf16x8 pa1 = *reinterpret_cast<const bf16x8*>(
                    &Ps1[qloc * 64 + ((kki * 32 + quad * 8) ^ rsw)]);
#pragma unroll
                for (int nb = 0; nb < 4; nb++) {
                    bf16x8 vb = *reinterpret_cast<const bf16x8*>(
                        &VTs[cur + (nb * 16 + ln16) * 64 + ((kki * 32 + quad * 8) ^ rsw)]);
                    accO1[nb] = MFMA16(vb, pa1, accO1[nb]);
                }
                accO1[4] = MFMA16(vones, pa1, accO1[4]);
            }
        }
    }

    const float linv1 = 1.0f / accO1[4][0];
    const float linv2 = 1.0f / accO2[4][0];
    const size_t zr1 = ((size_t)b * Tn + q01 + qloc) * Dm + h * 64;
    const size_t zr2 = ((size_t)b * Tn + q02 + qloc) * Dm + h * 64;
#pragma unroll
    for (int nb = 0; nb < 4; nb++) {
        bf16x4 v1, v2;
#pragma unroll
        for (int r = 0; r < 4; r++) {
            v1[r] = (bf16)(accO1[nb][r] * linv1);
            v2[r] = (bf16)(accO2[nb][r] * linv2);
        }
        *reinterpret_cast<bf16x4*>(z + zr1 + nb * 16 + quad * 4) = v1;
        *reinterpret_cast<bf16x4*>(z + zr2 + nb * 16 + quad * 4) = v2;
    }
}

// ---------------------------------------------------------------------------
extern "C" void kernel_launch(void* const* d_in, const int* in_sizes, int n_in,
                              void* d_out, int out_size, void* d_ws, size_t ws_size,
                              hipStream_t stream)
{
    constexpr int B = 2, T = 2048, D = 1024;
    constexpr int M = B * T;  // 4096

    const float* X    = (const float*)d_in[0];
    const float* Wqkv = (const float*)d_in[1];
    const float* Wout = (const float*)d_in[2];
    float* out = (float*)d_out;

    // ws: qk [M][2048] 16 MiB | vt [1024][M] 8 MiB | z [M][1024] 8 MiB
    //   | Woutbf [1024][1024] 2 MiB
    bf16* qk  = (bf16*)d_ws;
    bf16* vt  = qk + (size_t)M * 2048;
    bf16* zbf = vt + (size_t)1024 * M;
    bf16* Woutbf = zbf + (size_t)M * 1024;
    // d_out as scratch until gemm_out writes it (Xbf 8 MiB + Wqkvbf 6 MiB <= 16)
    bf16* Xbf    = (bf16*)d_out;
    bf16* Wqkvbf = Xbf + (size_t)M * D;

    dim3 blk(256);
    const int n1 = M * D / 8, n2 = 3 * D * D / 8, n3 = D * D / 8;
    cvt3<<<(n1 + n2 + n3 + 255) / 256, blk, 0, stream>>>(
        X, Wqkv, Wout, Xbf, Woutbf, n1, n1 + n2, n1 + n2 + n3);

    gemm_qkv<<<dim3(24, 32), blk, 0, stream>>>(Xbf, Wqkvbf, qk, vt);

    attn_flash9<<<dim3(512), blk, 0, stream>>>(qk, vt, zbf);

    gemm_out<<<dim3(512), blk, 0, stream>>>(zbf, Woutbf, out);
}